// Round 9
// baseline (104.626 us; speedup 1.0000x reference)
//
#include <hip/hip_runtime.h>
#include <hip/hip_bf16.h>

#define NTOT 8192   // 2B
#define BB   4096   // B
#define DD   256    // D
#define NWAVES 2048
#define NBLK (NWAVES / 4)   // 512 blocks = 2/CU
#define NCHUNK 33024        // sum_{r<128} (512 - 4r)

typedef __attribute__((ext_vector_type(8))) short short8v;  // 8 bf16 = 4 VGPR
typedef __attribute__((ext_vector_type(4))) float f32x4;

__device__ __forceinline__ unsigned short f2bf(float f) {
    union { __hip_bfloat16 h; unsigned short u; } cv;
    cv.h = __float2bfloat16(f);
    return cv.u;
}

// One wave per pair r: normalize x1[r], x2[r]; emit bf16 z rows r and r+BB;
// fp32 selfdot (z.z) and posdot (z1.z2). Blocks 0-7 zero S; block 0 zeros out.
__global__ __launch_bounds__(256) void k_normalize(
    const float* __restrict__ x1, const float* __restrict__ x2,
    unsigned short* __restrict__ zbf,
    float* __restrict__ selfdot, float* __restrict__ posdot,
    float* __restrict__ S, float* __restrict__ out)
{
    if (blockIdx.x < 8) {
        float4 z4 = make_float4(0.f, 0.f, 0.f, 0.f);
        *(float4*)(S + blockIdx.x * 1024 + threadIdx.x * 4) = z4;
        if (blockIdx.x == 0 && threadIdx.x == 0) out[0] = 0.0f;
    }

    const int lane = threadIdx.x & 63;
    const int pair = blockIdx.x * 4 + (threadIdx.x >> 6);

    const float4 a = *(const float4*)(x1 + (size_t)pair * DD + lane * 4);
    const float4 b = *(const float4*)(x2 + (size_t)pair * DD + lane * 4);

    float s1 = a.x * a.x + a.y * a.y + a.z * a.z + a.w * a.w;
    float s2 = b.x * b.x + b.y * b.y + b.z * b.z + b.w * b.w;
#pragma unroll
    for (int off = 1; off < 64; off <<= 1) {
        s1 += __shfl_xor(s1, off);
        s2 += __shfl_xor(s2, off);
    }
    const float inv1 = 1.0f / fmaxf(sqrtf(s1), 1e-12f);
    const float inv2 = 1.0f / fmaxf(sqrtf(s2), 1e-12f);

    const float4 z1 = make_float4(a.x * inv1, a.y * inv1, a.z * inv1, a.w * inv1);
    const float4 z2 = make_float4(b.x * inv2, b.y * inv2, b.z * inv2, b.w * inv2);

    float sd1 = z1.x * z1.x + z1.y * z1.y + z1.z * z1.z + z1.w * z1.w;
    float sd2 = z2.x * z2.x + z2.y * z2.y + z2.z * z2.z + z2.w * z2.w;
    float pd  = z1.x * z2.x + z1.y * z2.y + z1.z * z2.z + z1.w * z2.w;
#pragma unroll
    for (int off = 1; off < 64; off <<= 1) {
        sd1 += __shfl_xor(sd1, off);
        sd2 += __shfl_xor(sd2, off);
        pd  += __shfl_xor(pd, off);
    }

    ushort4 u1, u2;
    u1.x = f2bf(z1.x); u1.y = f2bf(z1.y); u1.z = f2bf(z1.z); u1.w = f2bf(z1.w);
    u2.x = f2bf(z2.x); u2.y = f2bf(z2.y); u2.z = f2bf(z2.z); u2.w = f2bf(z2.w);
    *(ushort4*)(zbf + (size_t)pair * DD + lane * 4) = u1;
    *(ushort4*)(zbf + (size_t)(pair + BB) * DD + lane * 4) = u2;

    if (lane == 0) {
        selfdot[pair] = sd1;
        selfdot[pair + BB] = sd2;
        posdot[pair] = pd;
        posdot[pair + BB] = pd;
    }
}

// BARRIER-FREE per-wave pipelined triangle GEMM (round 9). Rounds 3-8 showed
// the block-wide __syncthreads (vmcnt(0)+lgkmcnt(0) lockstep of all waves)
// is the structural stall. Here each wave runs a PRIVATE double-buffered
// pipeline: 2 x 8 KB LDS (4 waves x 16 KB = 64 KB/block, 2 blocks/CU), 16-col
// chunks, counted `s_waitcnt vmcnt(8)` (chunk s complete; s+1,s+2 in flight;
// NEVER 0 mid-loop -- T4). No __syncthreads in the kernel. Triangle at 64-row
// tile granularity: tile r has 512-4r chunks (4 diag + upper); 33024 chunks
// flattened, wave v takes [129v/8, 129(v+1)/8) = 16-17 chunks. Upper chunks
// credit row sums (in-reg) AND column sums (2 shfl + atomicAdd). Staging uses
// pre-swizzled source + linear LDS dest (G21); reads XOR the same involution.
__global__ __launch_bounds__(256, 2) void k_simsum(
    const unsigned short* __restrict__ zbf, float* __restrict__ S)
{
    __shared__ char Bsh[4][2][8192];   // per-wave double buffer, 64 KB total

    const int tid  = threadIdx.x;
    const int lane = tid & 63;
    const int wv   = tid >> 6;
    const int frow = lane & 15;
    const int g    = lane >> 4;
    const int v    = blockIdx.x * 4 + wv;

    const int sBeg = (129 * v) >> 3;
    const int sEnd = (129 * (v + 1)) >> 3;

    // decode sBeg -> (tile r, chunk-in-tile t); tile r has 512-4r chunks
    int r = 0, C = 0;
    while (C + 512 - 4 * r <= sBeg) { C += 512 - 4 * r; ++r; }
    int t = sBeg - C;

    // staging source offsets (pre-swizzled): instr ri covers local cols
    // lc = ri*2 + (lane>>5); src = lc*512 + ((lane&31)^(lc&7))*16.
    // LDS dest linear: ri*1024 + lane*16. (col0 is 16-aligned so lc&7 is
    // the same parity the read-side XOR uses.)
    int srcOff[8];
#pragma unroll
    for (int ri = 0; ri < 8; ++ri) {
        const int lc = ri * 2 + (lane >> 5);
        srcOff[ri] = lc * 512 + (((lane & 31) ^ (lc & 7)) << 4);
    }

    // swizzled ds_read addresses (carry-free XOR, proven round-3)
    const int base0 = frow * 512 + g * 16;
    const int bmask = (frow & 7) << 4;
    int addrs[8];
#pragma unroll
    for (int kk = 0; kk < 8; ++kk) addrs[kk] = (base0 + kk * 64) ^ bmask;

    char* buf0 = &Bsh[wv][0][0];
    char* buf1 = &Bsh[wv][1][0];

#define STAGE(r_, t_, bufp)                                                        \
    do {                                                                           \
        const char* gs_ = (const char*)zbf + (size_t)(r_) * 32768                  \
                          + (size_t)(t_) * 8192;                                   \
        _Pragma("unroll")                                                          \
        for (int ri_ = 0; ri_ < 8; ++ri_)                                          \
            __builtin_amdgcn_global_load_lds(                                      \
                (const __attribute__((address_space(1))) unsigned int*)(gs_ + srcOff[ri_]), \
                (__attribute__((address_space(3))) unsigned int*)((bufp) + ri_ * 1024 + lane * 16), \
                16, 0, 0);                                                         \
    } while (0)

#define ADV(rr, tt)                                                                \
    do { if (++(tt) >= 512 - 4 * (rr)) { ++(rr); (tt) = 0; } } while (0)

    // ---- A: 64 rows x 256 k in registers for tile r ----
    short8v Afrag[4][8];
#pragma unroll
    for (int rt = 0; rt < 4; ++rt) {
        const unsigned short* ap =
            zbf + (size_t)(64 * r + rt * 16 + frow) * DD + g * 8;
#pragma unroll
        for (int kk = 0; kk < 8; ++kk)
            Afrag[rt][kk] = *(const short8v*)(ap + kk * 32);
    }

    float rs[4][4];
#pragma unroll
    for (int rt = 0; rt < 4; ++rt)
#pragma unroll
        for (int q = 0; q < 4; ++q) rs[rt][q] = 0.0f;

    // prologue: stage chunks s, s+1
    STAGE(r, t, buf0);
    int pr = r, pt = t;
    ADV(pr, pt);
    STAGE(pr, pt, buf1);
    ADV(pr, pt);                       // prefetch pointer now at s+2

    int cur = 0;
    int cr = r, ct = t;
    for (int s = sBeg; s < sEnd; ++s) {
        if (s + 1 < sEnd) {
            asm volatile("s_waitcnt vmcnt(8)" ::: "memory");
        } else {
            asm volatile("s_waitcnt vmcnt(0)" ::: "memory");
        }
        __builtin_amdgcn_sched_barrier(0);

        char* buf = cur ? buf1 : buf0;

        // ---- compute chunk (cr, ct): 16 cols, full K=256 ----
        f32x4 acc[4];
#pragma unroll
        for (int rt = 0; rt < 4; ++rt) {
            acc[rt][0] = 0.0f; acc[rt][1] = 0.0f;
            acc[rt][2] = 0.0f; acc[rt][3] = 0.0f;
        }
#pragma unroll
        for (int kk = 0; kk < 8; ++kk) {
            const short8v bfr = *(const short8v*)(buf + addrs[kk]);
#pragma unroll
            for (int rt = 0; rt < 4; ++rt)
                acc[rt] = __builtin_amdgcn_mfma_f32_16x16x32_bf16(
                    Afrag[rt][kk], bfr, acc[rt], 0, 0, 0);
        }

        float cs = 0.0f;
#pragma unroll
        for (int rt = 0; rt < 4; ++rt)
#pragma unroll
            for (int q = 0; q < 4; ++q) {
                const float e = exp2f(acc[rt][q] * 2.8853900817779268f);
                rs[rt][q] += e;
                cs += e;
            }
        if (ct >= 4) {   // strictly-upper chunk: credit column sums
            cs += __shfl_xor(cs, 16);
            cs += __shfl_xor(cs, 32);
            if (lane < 16)
                atomicAdd(&S[64 * cr + 16 * ct + frow], cs);
        }

        // stage chunk s+2 into the buffer just consumed
        if (s + 2 < sEnd) { STAGE(pr, pt, buf); ADV(pr, pt); }

        // advance compute pointer; on tile crossing flush rows + reload A
        if (s + 1 < sEnd) {
            int nr = cr, nt = ct + 1;
            if (nt >= 512 - 4 * cr) { nr = cr + 1; nt = 0; }
            if (nr != cr) {
#pragma unroll
                for (int rt = 0; rt < 4; ++rt)
#pragma unroll
                    for (int q = 0; q < 4; ++q) {
                        float val = rs[rt][q];
                        val += __shfl_xor(val, 1);
                        val += __shfl_xor(val, 2);
                        val += __shfl_xor(val, 4);
                        val += __shfl_xor(val, 8);
                        if (frow == 0)
                            atomicAdd(&S[64 * cr + rt * 16 + g * 4 + q], val);
                        rs[rt][q] = 0.0f;
                    }
#pragma unroll
                for (int rt = 0; rt < 4; ++rt) {
                    const unsigned short* ap =
                        zbf + (size_t)(64 * nr + rt * 16 + frow) * DD + g * 8;
#pragma unroll
                    for (int kk = 0; kk < 8; ++kk)
                        Afrag[rt][kk] = *(const short8v*)(ap + kk * 32);
                }
            }
            cr = nr; ct = nt;
        }
        cur ^= 1;
    }

    // final row-sum flush for tile cr
#pragma unroll
    for (int rt = 0; rt < 4; ++rt)
#pragma unroll
        for (int q = 0; q < 4; ++q) {
            float val = rs[rt][q];
            val += __shfl_xor(val, 1);
            val += __shfl_xor(val, 2);
            val += __shfl_xor(val, 4);
            val += __shfl_xor(val, 8);
            if (frow == 0)
                atomicAdd(&S[64 * cr + rt * 16 + g * 4 + q], val);
        }
#undef STAGE
#undef ADV
}

// 32 blocks x 256 threads: each thread one row. S[i] holds the full exp row
// sum (incl. diagonal); subtract fp32 diagonal, log, subtract numerator.
__global__ __launch_bounds__(256) void k_final(
    const float* __restrict__ S, const float* __restrict__ selfdot,
    const float* __restrict__ posdot, float* __restrict__ out)
{
    __shared__ float red[4];
    const int tid = threadIdx.x;
    const int i = blockIdx.x * 256 + tid;
    const float den = fmaxf(S[i] - expf(2.0f * selfdot[i]), 1e-8f);
    float acc = logf(den) - 2.0f * posdot[i];
#pragma unroll
    for (int off = 1; off < 64; off <<= 1) acc += __shfl_xor(acc, off);
    if ((tid & 63) == 0) red[tid >> 6] = acc;
    __syncthreads();
    if (tid == 0)
        atomicAdd(out, (red[0] + red[1] + red[2] + red[3]) * (1.0f / (float)NTOT));
}

extern "C" void kernel_launch(void* const* d_in, const int* in_sizes, int n_in,
                              void* d_out, int out_size, void* d_ws, size_t ws_size,
                              hipStream_t stream) {
    const float* x1 = (const float*)d_in[0];
    const float* x2 = (const float*)d_in[1];
    float* out = (float*)d_out;

    char* ws = (char*)d_ws;
    unsigned short* zbf = (unsigned short*)ws;                       // 4 MB
    size_t off = (size_t)NTOT * DD * sizeof(unsigned short);
    float* S = (float*)(ws + off);                                   // 32 KB
    off += (size_t)NTOT * sizeof(float);
    float* selfdot = (float*)(ws + off);                             // 32 KB
    off += (size_t)NTOT * sizeof(float);
    float* posdot = (float*)(ws + off);                              // 32 KB

    k_normalize<<<dim3(BB / 4), dim3(256), 0, stream>>>(x1, x2, zbf, selfdot, posdot, S, out);
    k_simsum<<<dim3(NBLK), dim3(256), 0, stream>>>(zbf, S);
    k_final<<<dim3(NTOT / 256), dim3(256), 0, stream>>>(S, selfdot, posdot, out);
}